// Round 8
// baseline (82.595 us; speedup 1.0000x reference)
//
#include <hip/hip_runtime.h>

#define IMG_H 720
#define IMG_W 1280
#define IMG_N 2

#define TX 64          // output tile width
#define TY 16          // output tile height
#define NBX (IMG_W / TX)   // 20
#define NBY (IMG_H / TY)   // 45
#define NBLK (IMG_N * NBX * NBY)  // 1800
#define LW 72          // LDS row stride in words (2-way b128 conflict = free, m136)
#define LH (TY + 6)    // 22
#define NCHUNK (LH * (LW / 4))  // 396 float4 chunks per tile

#define PROBE_REP 4

// k = sqrt(50 * log2(e)); exponent: -(k*v - k*c)^2 - (r2)*S2SCALE
#define KSCALE 8.493218148592486f
#define INVK   0.11774100235949044f
#define S2SCALE 0.028853900817779268f  // 1/(50*ln2)

#if defined(__has_builtin)
#if __has_builtin(__builtin_amdgcn_exp2f)
#define EXP2(x) __builtin_amdgcn_exp2f(x)
#else
#define EXP2(x) exp2f(x)
#endif
#if __has_builtin(__builtin_amdgcn_rcpf)
#define RCP(x) __builtin_amdgcn_rcpf(x)
#else
#define RCP(x) (1.0f / (x))
#endif
#else
#define EXP2(x) exp2f(x)
#define RCP(x) (1.0f / (x))
#endif

// Per-row taps. fk values are k-pre-scaled; acc_iw accumulates in k-domain.
__device__ __forceinline__ void do_row(const float* __restrict__ rowptr,
                                       const float ck[4], float acc_w[4],
                                       float acc_iw[4], const int ry2) {
    float4 a = *(const float4*)(rowptr);
    float4 bb = *(const float4*)(rowptr + 4);
    float4 d4 = *(const float4*)(rowptr + 8);
    float fk[12] = {a.x, a.y, a.z, a.w, bb.x, bb.y, bb.z, bb.w,
                    d4.x, d4.y, d4.z, d4.w};
#pragma unroll
    for (int p = 0; p < 4; ++p) {
#pragma unroll
        for (int dx = 0; dx < 7; ++dx) {
            const float s2 = -(float)(ry2 + (dx - 3) * (dx - 3)) * S2SCALE;
            float v = fk[p + dx];
            float dd = v - ck[p];
            float e = fmaf(-dd, dd, s2);   // v_fma with neg modifier: 1 inst
            float w = EXP2(e);
            acc_w[p] += w;
            acc_iw[p] = fmaf(w, v, acc_iw[p]);
        }
    }
}

__device__ __forceinline__ void bilateral_body(
    const float* __restrict__ I, float* __restrict__ O, int b,
    float (*S)[LW]) {
    int bx = b % NBX;
    int by = (b / NBX) % NBY;
    int n = b / (NBX * NBY);
    int tx0 = bx * TX, ty0 = by * TY;

    const float* img = I + (size_t)n * IMG_H * IMG_W;
    int tid = threadIdx.x;

    // ---- stage (k-pre-scaled) ----
    bool interior = (bx >= 1) && (bx <= NBX - 2) && (by >= 1) && (by <= NBY - 2);
    if (interior) {
#pragma unroll
        for (int i = 0; i < 2; ++i) {
            int id = tid + i * 256;
            if (id < NCHUNK) {
                int r = id / (LW / 4);
                int q = id % (LW / 4);
                int gy = ty0 - 3 + r, gx = tx0 - 3 + q * 4;
                float4 v = *(const float4*)(img + gy * IMG_W + gx);
                v.x *= KSCALE; v.y *= KSCALE; v.z *= KSCALE; v.w *= KSCALE;
                *(float4*)(&S[r][q * 4]) = v;
            }
        }
    } else {
#pragma unroll
        for (int i = 0; i < 7; ++i) {
            int idx = tid + i * 256;
            if (idx < LH * LW) {
                int r = idx / LW, col = idx % LW;
                int gy = ty0 - 3 + r, gx = tx0 - 3 + col;
                float v = 0.0f;
                if (col < 70 && gy >= 0 && gy < IMG_H && gx >= 0 && gx < IMG_W)
                    v = img[gy * IMG_W + gx];
                S[r][col] = v * KSCALE;
            }
        }
    }
    __syncthreads();

    // ---- compute: 4 consecutive output pixels per thread ----
    int px = tid & 15;
    int py = tid >> 4;
    int x0 = px * 4;

    float acc_w[4] = {0.f, 0.f, 0.f, 0.f};
    float acc_iw[4] = {0.f, 0.f, 0.f, 0.f};
    float ck[4];

    // Row 3 first: center values come from this row's registers.
    {
        const float* row = &S[py + 3][x0];
        float4 a = *(const float4*)(row);
        float4 bb = *(const float4*)(row + 4);
        float4 d4 = *(const float4*)(row + 8);
        float fk[12] = {a.x, a.y, a.z, a.w, bb.x, bb.y, bb.z, bb.w,
                        d4.x, d4.y, d4.z, d4.w};
#pragma unroll
        for (int p = 0; p < 4; ++p) ck[p] = fk[3 + p];
#pragma unroll
        for (int p = 0; p < 4; ++p) {
#pragma unroll
            for (int dx = 0; dx < 7; ++dx) {
                const float s2 = -(float)((dx - 3) * (dx - 3)) * S2SCALE;
                float v = fk[p + dx];
                float dd = v - ck[p];
                float e = fmaf(-dd, dd, s2);
                float w = EXP2(e);
                acc_w[p] += w;
                acc_iw[p] = fmaf(w, v, acc_iw[p]);
            }
        }
    }
    do_row(&S[py + 0][x0], ck, acc_w, acc_iw, 9);
    do_row(&S[py + 1][x0], ck, acc_w, acc_iw, 4);
    do_row(&S[py + 2][x0], ck, acc_w, acc_iw, 1);
    do_row(&S[py + 4][x0], ck, acc_w, acc_iw, 1);
    do_row(&S[py + 5][x0], ck, acc_w, acc_iw, 4);
    do_row(&S[py + 6][x0], ck, acc_w, acc_iw, 9);

    float* out = O + ((size_t)n * IMG_H + (ty0 + py)) * IMG_W + tx0 + x0;
    float4 rr;
    rr.x = acc_iw[0] * RCP(acc_w[0]) * INVK;
    rr.y = acc_iw[1] * RCP(acc_w[1]) * INVK;
    rr.z = acc_iw[2] * RCP(acc_w[2]) * INVK;
    rr.w = acc_iw[3] * RCP(acc_w[3]) * INVK;
    *(float4*)out = rr;
}

// Real kernel: identical to round 6.
__global__ __launch_bounds__(256, 8) void bilateral_tile(
    const float* __restrict__ I, float* __restrict__ O) {
    __shared__ float S[LH][LW];
    bilateral_body(I, O, blockIdx.x, S);
}

// Probe: same body, 4x duplicated grid, writes to d_ws. Exists solely to
// outrank the harness's ~40us fill kernels in rocprof top-5 so we finally
// see VGPR_Count / VALUBusy / LDS conflicts for this exact code.
__global__ __launch_bounds__(256, 8) void bilateral_probe(
    const float* __restrict__ I, float* __restrict__ O) {
    __shared__ float S[LH][LW];
    bilateral_body(I, O, blockIdx.x % NBLK, S);
}

extern "C" void kernel_launch(void* const* d_in, const int* in_sizes, int n_in,
                              void* d_out, int out_size, void* d_ws, size_t ws_size,
                              hipStream_t stream) {
    const float* I = (const float*)d_in[0];
    float* O = (float*)d_out;

    bilateral_tile<<<NBLK, 256, 0, stream>>>(I, O);

    // Diagnostic probe (writes scratch only; d_out already final).
    const size_t probe_need = (size_t)IMG_N * IMG_H * IMG_W * sizeof(float);
    if (d_ws != nullptr && ws_size >= probe_need) {
        float* W = (float*)d_ws;
        bilateral_probe<<<NBLK * PROBE_REP, 256, 0, stream>>>(I, W);
    }
}

// Round 11
// 19.450 us; speedup vs baseline: 4.2465x; 4.2465x over previous
//
#include <hip/hip_runtime.h>

#define IMG_H 720
#define IMG_W 1280
#define HW (IMG_H * IMG_W)

#define TX 32
#define TY 16
#define NBX (IMG_W / TX)   // 40
#define NBY (IMG_H / TY)   // 45
#define NBLK (NBX * NBY)   // 1800 blocks; each block does BOTH images
#define LW2 40             // f2 columns per LDS row (38 used)
#define LH (TY + 6)        // 22

// k = sqrt(50*log2(e)); w = exp2(-((k*v - k*c)^2 + r2*S2SCALE))
#define KSCALE 8.493218148592486f
#define INVK   0.11774100235949044f
#define S2SCALE 0.028853900817779268f  // 1/(50*ln2)

typedef float f2 __attribute__((ext_vector_type(2)));

#if defined(__has_builtin)
#if __has_builtin(__builtin_amdgcn_exp2f)
#define EXP2(x) __builtin_amdgcn_exp2f(x)
#else
#define EXP2(x) exp2f(x)
#endif
#if __has_builtin(__builtin_amdgcn_rcpf)
#define RCP(x) __builtin_amdgcn_rcpf(x)
#else
#define RCP(x) (1.0f / (x))
#endif
#else
#define EXP2(x) exp2f(x)
#define RCP(x) (1.0f / (x))
#endif

// spatial sums ry2+rx2 ∈ {0,1,2,4,5,8,9,10,13,18} -> index 0..9
__device__ constexpr int MIDX[19] = {0, 1, 2, -1, 3, 4, -1, -1, 5, 6,
                                     7, -1, -1, 8, -1, -1, -1, -1, 9};

// One packed tap = this (dy,dx) tap for BOTH images of one pixel.
// Native v2f32 ops -> ISel emits v_pk_add_f32 / v_pk_fma_f32 with correct
// op_sel bits (R9/R10 lesson: hand-written VOP3P asm had wrong hi-half
// semantics; never hand-encode modifier defaults you can't verify).
__device__ __forceinline__ void tap(f2 v, f2 nck, f2 s2p, f2& aw, f2& aiw) {
    f2 dd = v + nck;                               // v - ck
    f2 e = __builtin_elementwise_fma(dd, dd, s2p); // dd^2 + s2 (positive)
    f2 w;
    w.x = EXP2(-e.x);   // neg folds into v_exp_f32 src modifier
    w.y = EXP2(-e.y);
    aw += w;
    aiw = __builtin_elementwise_fma(w, v, aiw);
}

template <int RY2>
__device__ __forceinline__ void do_row_t(const f2* __restrict__ rowptr,
                                         f2 nck0, f2 nck1,
                                         f2& aw0, f2& aiw0, f2& aw1, f2& aiw1,
                                         const f2 (&s2)[10]) {
    f2 f[8];
    *(float4*)(&f[0]) = *(const float4*)(rowptr + 0);
    *(float4*)(&f[2]) = *(const float4*)(rowptr + 2);
    *(float4*)(&f[4]) = *(const float4*)(rowptr + 4);
    *(float4*)(&f[6]) = *(const float4*)(rowptr + 6);
#pragma unroll
    for (int dx = 0; dx < 7; ++dx) {
        const int sidx = MIDX[RY2 + (dx - 3) * (dx - 3)];  // compile-time
        tap(f[dx], nck0, s2[sidx], aw0, aiw0);
        tap(f[dx + 1], nck1, s2[sidx], aw1, aiw1);
    }
}

__global__ __launch_bounds__(256, 8) void bilateral_pk(
    const float* __restrict__ I, float* __restrict__ O) {
    int b = blockIdx.x;
    int bx = b % NBX, by = b / NBX;
    int tx0 = bx * TX, ty0 = by * TY;
    int tid = threadIdx.x;

    __shared__ f2 S[LH][LW2];
    const float* img0 = I;
    const float* img1 = I + HW;

    // ---- stage both images, interleaved {img0,img1} per f2, k-pre-scaled ----
    bool interior = (bx >= 1) && (bx <= NBX - 2) && (by >= 1) && (by <= NBY - 2);
    if (interior) {
        // 220 chunks of 4 f2-cols; interior never needs clamping
        // (bx<=38 -> max gx+3 = tx0+36 <= 1252 < 1280; bx>=1 -> min gx = 29).
        if (tid < LH * (LW2 / 4)) {
            int r = tid / (LW2 / 4), q = tid % (LW2 / 4);
            int gy = ty0 - 3 + r, gx = tx0 - 3 + q * 4;
            float4 a0 = *(const float4*)(img0 + gy * IMG_W + gx);
            float4 a1 = *(const float4*)(img1 + gy * IMG_W + gx);
            float4 w0, w1;
            w0.x = a0.x * KSCALE; w0.y = a1.x * KSCALE;
            w0.z = a0.y * KSCALE; w0.w = a1.y * KSCALE;
            w1.x = a0.z * KSCALE; w1.y = a1.z * KSCALE;
            w1.z = a0.w * KSCALE; w1.w = a1.w * KSCALE;
            *(float4*)(&S[r][q * 4]) = w0;
            *(float4*)(&S[r][q * 4 + 2]) = w1;
        }
    } else {
#pragma unroll
        for (int i = 0; i < 4; ++i) {
            int idx = tid + i * 256;
            if (idx < LH * LW2) {
                int r = idx / LW2, c = idx % LW2;
                int gy = ty0 - 3 + r, gx = tx0 - 3 + c;
                float v0 = 0.f, v1 = 0.f;
                if (gy >= 0 && gy < IMG_H && gx >= 0 && gx < IMG_W) {
                    v0 = img0[gy * IMG_W + gx];
                    v1 = img1[gy * IMG_W + gx];
                }
                f2 t = {v0 * KSCALE, v1 * KSCALE};
                S[r][c] = t;
            }
        }
    }
    __syncthreads();

    // ---- spatial-constant pairs, kept live in VGPRs ----
    const float sv[10] = {0.f, 1.f, 2.f, 4.f, 5.f, 8.f, 9.f, 10.f, 13.f, 18.f};
    f2 s2reg[10];
#pragma unroll
    for (int j = 0; j < 10; ++j) {
        float s = sv[j] * S2SCALE;
        s2reg[j].x = s;
        s2reg[j].y = s;
        asm("" : "+v"(s2reg[j]));  // opaque: keep as a live register pair
    }

    // ---- compute: 2 pixel-pairs (4 outputs) per thread ----
    int px = tid & 15;   // x-group of 2 pixels
    int py = tid >> 4;   // row in tile
    int x0 = px * 2;

    f2 aw0 = {0.f, 0.f}, aw1 = {0.f, 0.f};
    f2 aiw0 = {0.f, 0.f}, aiw1 = {0.f, 0.f};
    f2 nck0, nck1;

    // Row 3 first: centers come from this row's registers.
    {
        const f2* rowptr = &S[py + 3][x0];
        f2 f[8];
        *(float4*)(&f[0]) = *(const float4*)(rowptr + 0);
        *(float4*)(&f[2]) = *(const float4*)(rowptr + 2);
        *(float4*)(&f[4]) = *(const float4*)(rowptr + 4);
        *(float4*)(&f[6]) = *(const float4*)(rowptr + 6);
        nck0 = -f[3];
        nck1 = -f[4];
#pragma unroll
        for (int dx = 0; dx < 7; ++dx) {
            const int sidx = MIDX[(dx - 3) * (dx - 3)];
            tap(f[dx], nck0, s2reg[sidx], aw0, aiw0);
            tap(f[dx + 1], nck1, s2reg[sidx], aw1, aiw1);
        }
    }
    do_row_t<9>(&S[py + 0][x0], nck0, nck1, aw0, aiw0, aw1, aiw1, s2reg);
    do_row_t<4>(&S[py + 1][x0], nck0, nck1, aw0, aiw0, aw1, aiw1, s2reg);
    do_row_t<1>(&S[py + 2][x0], nck0, nck1, aw0, aiw0, aw1, aiw1, s2reg);
    do_row_t<1>(&S[py + 4][x0], nck0, nck1, aw0, aiw0, aw1, aiw1, s2reg);
    do_row_t<4>(&S[py + 5][x0], nck0, nck1, aw0, aiw0, aw1, aiw1, s2reg);
    do_row_t<9>(&S[py + 6][x0], nck0, nck1, aw0, aiw0, aw1, aiw1, s2reg);

    int oy = ty0 + py;
    float2 r0, r1;
    r0.x = aiw0.x * RCP(aw0.x) * INVK;  // img0, col x0
    r0.y = aiw1.x * RCP(aw1.x) * INVK;  // img0, col x0+1
    r1.x = aiw0.y * RCP(aw0.y) * INVK;  // img1, col x0
    r1.y = aiw1.y * RCP(aw1.y) * INVK;  // img1, col x0+1
    *(float2*)(O + (size_t)oy * IMG_W + tx0 + x0) = r0;
    *(float2*)(O + HW + (size_t)oy * IMG_W + tx0 + x0) = r1;
}

extern "C" void kernel_launch(void* const* d_in, const int* in_sizes, int n_in,
                              void* d_out, int out_size, void* d_ws, size_t ws_size,
                              hipStream_t stream) {
    const float* I = (const float*)d_in[0];
    float* O = (float*)d_out;
    bilateral_pk<<<NBLK, 256, 0, stream>>>(I, O);
}